// Round 16
// baseline (273.351 us; speedup 1.0000x reference)
//
#include <hip/hip_runtime.h>
#include <hip/hip_bf16.h>

#define HWPX 4096

typedef __attribute__((ext_vector_type(8))) short short8v;
typedef __attribute__((ext_vector_type(4))) float f32x4;
typedef __attribute__((ext_vector_type(16))) float f32x16;
#define MFMA32(a,b,c) __builtin_amdgcn_mfma_f32_32x32x16_bf16(a,b,c,0,0,0)

__device__ __forceinline__ float sigf(float x){ return 1.0f/(1.0f+__expf(-x)); }
__device__ __forceinline__ unsigned short f2bf(float f){
  __hip_bfloat16 h = __float2bfloat16(f);
  unsigned short u; __builtin_memcpy(&u, &h, sizeof(u)); return u;
}
__device__ __forceinline__ float bf2f(unsigned short u){
  return __uint_as_float(((unsigned)u)<<16);
}
__device__ __forceinline__ void gl2lds16(const void* g, void* l){
  __builtin_amdgcn_global_load_lds((const __attribute__((address_space(1))) void*)g,
                                   (__attribute__((address_space(3))) void*)l, 16, 0, 0);
}

// ---------------- K1: merged prep (round-5 weight layout + x11) / rc / x2mean zero ----------------
__global__ __launch_bounds__(256) void k_pre(const float* __restrict__ x,
                                             const float* __restrict__ wb1,
                                             const float* __restrict__ wb2,
                                             const float* __restrict__ wcat,
                                             const float* __restrict__ gnb,
                                             unsigned short* __restrict__ xb,
                                             float* __restrict__ hwbuf,
                                             unsigned short* __restrict__ wimg,
                                             unsigned short* __restrict__ wcimg,
                                             float* __restrict__ x11,
                                             float* __restrict__ x2mean){
  int bid = blockIdx.x, tid = threadIdx.x;
  if (bid >= 1088){
    int idx = (bid - 1088)*2048 + tid*8;
    f32x4 z = {0.f,0.f,0.f,0.f};
    *(f32x4*)(x2mean + idx) = z;
    *(f32x4*)(x2mean + idx + 4) = z;
    return;
  }
  if (bid >= 1024){
    int bid2 = bid - 1024;
    for (int idx = bid2*256 + tid; idx < 73728; idx += 64*256){
      int f = idx >> 9, r = idx & 511, lane = r >> 3, j = r & 7;
      int qc = f / 36, rem = f % 36, tap = rem >> 2, kc = rem & 3;
      int q = qc >> 1, conv = qc & 1, kf = kc >> 1, cot = kc & 1;
      int co = cot*32 + (lane & 31);
      int ci = q*32 + kf*16 + (lane >> 5)*8 + j;
      const float* src = conv ? wb2 : wb1;
      wimg[idx] = f2bf(src[(co*64 + ci)*9 + tap]);
    }
    if (bid2 == 0){
      for (int idx = tid; idx < 8192; idx += 256){
        int f = idx >> 9, r = idx & 511, lane = r >> 3, j = r & 7;
        int kfc = f >> 1, cot = f & 1;
        int o = cot*32 + (lane & 31);
        int ch = kfc*16 + (lane >> 5)*8 + j;
        wcimg[idx] = f2bf(wcat[o*128 + ch]);
      }
      if (tid < 64){
        float g = gnb[tid];
        float m = g;
        for (int s=32; s; s>>=1) m = fmaxf(m, __shfl_xor(m, s));
        float e = __expf(g-m);
        float se = e;
        for (int s=32; s; s>>=1) se += __shfl_xor(se, s);
        x11[tid] = e/se;
      }
    }
    return;
  }
  // ---- rc ----
  int g = bid >> 3, slot = bid & 7;
  int col = tid & 63, wid = tid >> 6;
  __shared__ float rsm[8*64];
  __shared__ float csm[4*8*64];
  float colacc[8] = {0,0,0,0,0,0,0,0};
  const float* xbase = x + ((size_t)(g*64 + slot*8))*HWPX;
  for (int p=0;p<16;++p){
    int r = wid + 4*p;
    const float* src = xbase + r*64 + col;
    float v[8];
    #pragma unroll
    for (int e=0;e<8;e++) v[e] = src[(size_t)e*HWPX];
    unsigned pk[4];
    #pragma unroll
    for (int j=0;j<4;j++) pk[j] = (unsigned)f2bf(v[2*j]) | ((unsigned)f2bf(v[2*j+1])<<16);
    f32x4 st; __builtin_memcpy(&st, pk, 16);
    *(f32x4*)((char*)xb + (((size_t)(g*64+r))*8 + slot)*1024 + col*16) = st;
    #pragma unroll
    for (int e=0;e<8;e++){
      float s = v[e];
      s += __shfl_xor(s,1); s += __shfl_xor(s,2); s += __shfl_xor(s,4);
      s += __shfl_xor(s,8); s += __shfl_xor(s,16); s += __shfl_xor(s,32);
      if ((tid&63)==0) rsm[e*64+r] = s;
      colacc[e] += v[e];
    }
  }
  #pragma unroll
  for (int e=0;e<8;e++) csm[(wid*8+e)*64+col] = colacc[e];
  __syncthreads();
  float* hb = hwbuf + ((size_t)(g*64 + slot*8))*128;
  for (int idx=tid; idx<512; idx+=256){
    int e = idx>>6, r = idx&63;
    hb[e*128 + r] = rsm[e*64+r] * (1.0f/64.0f);
  }
  for (int idx=tid; idx<512; idx+=256){
    int e = idx>>6, c2 = idx&63;
    float s = csm[(0*8+e)*64+c2] + csm[(1*8+e)*64+c2] + csm[(2*8+e)*64+c2] + csm[(3*8+e)*64+c2];
    hb[e*128 + 64 + c2] = s * (1.0f/64.0f);
  }
}

// ---------------- conv compute (per q): dx-outer B-register reuse, A from LDS, cot-split ---------
template<int DIL>
__device__ __forceinline__ void conv_q(const char* INL, const char* WL,
                                       int ch2, int rquad, int cot, int lh, int l31, int lane,
                                       f32x16 (&acc)[4]){
  constexpr int conv = DIL - 1;
  constexpr int NROW = 4 + 2*DIL;
  #pragma unroll
  for (int kf=0; kf<2; ++kf){
    const char* ibase = INL + (kf*2 + lh)*1088 + (ch2*32 + 2 + l31)*16
                        + (rquad*4 + 2 - DIL)*4352;
    #pragma unroll
    for (int dxx=0; dxx<3; ++dxx){
      const char* ib = ibase + ((dxx-1)*DIL)*16;
      short8v Brow[NROW];
      #pragma unroll
      for (int i=0;i<NROW;++i) Brow[i] = *(const short8v*)(ib + i*4352);
      #pragma unroll
      for (int dyp=0;dyp<3;++dyp){
        int tap = dyp*3 + dxx;
        const char* wp = WL + (size_t)(((conv*9+tap)*4 + kf*2 + cot)*1024) + lane*16;
        short8v A0 = *(const short8v*)(wp);
        #pragma unroll
        for (int pt=0;pt<4;++pt)
          acc[pt] = MFMA32(A0, Brow[pt + dyp*DIL], acc[pt]);
      }
    }
  }
}

// ---------------- K4: conv blocks (0..1023, r12-exact) + gate2' blocks (1024..1151) --------------
// conv: 16 waves, round-5 staging, dx-outer B-reuse; LDS 147968, 1 block/CU.
// gate2' role: one g per block (1024 thr): hwmm matmul + sigmoid -> sigl/sigbuf, then gate stats.
__global__ __launch_bounds__(1024) void k_convcat(const unsigned short* __restrict__ xb,
                                                  const char* __restrict__ wgl,
                                                  const char* __restrict__ wcgl,
                                                  const float* __restrict__ hwbuf,
                                                  const float* __restrict__ whw,
                                                  const float* __restrict__ bhw,
                                                  float* __restrict__ sigbuf,
                                                  const float* __restrict__ gnw,
                                                  const float* __restrict__ gnb,
                                                  const float* __restrict__ bb1,
                                                  const float* __restrict__ bb2,
                                                  const float* __restrict__ a1p,
                                                  const float* __restrict__ a2p,
                                                  const float* __restrict__ bcat,
                                                  const float* __restrict__ x11,
                                                  float* __restrict__ wsum2,
                                                  float* __restrict__ wsum2b,
                                                  float* __restrict__ x2mean,
                                                  float* __restrict__ scsh){
  extern __shared__ char smem[];
  const int tid = threadIdx.x;

  if (blockIdx.x >= 1024){
    // ---------------- gate2' role: hwmm + sigmoid + GroupNorm gate statistics ----------------
    int g = blockIdx.x - 1024;           // 0..127
    float* hwl  = (float*)smem;          // 8192 f
    float* sigl = (float*)smem + 8192;   // 8192 f
    float* red  = (float*)smem + 16384;  // 256 f
    float* wl   = (float*)smem + 16640;  // 4096 f
    // stage hwbuf[g] (32KB) and w_hw (16KB)
    {
      const f32x4* src = (const f32x4*)(hwbuf + (size_t)g*8192);
      f32x4* dst = (f32x4*)hwl;
      dst[tid*2]   = src[tid*2];
      dst[tid*2+1] = src[tid*2+1];
      ((f32x4*)wl)[tid] = ((const f32x4*)whw)[tid];
    }
    __syncthreads();
    // matmul: sig = sigmoid(whw @ hw + bhw) -> sigl (LDS) + sigbuf (global)
    {
      int o = tid >> 4, kseg = tid & 15;
      float acc[8];
      float bv = bhw[o];
      #pragma unroll
      for (int j=0;j<8;j++) acc[j] = bv;
      for (int i=0;i<64;++i){
        float wv = wl[o*64 + i];
        #pragma unroll
        for (int j=0;j<8;j++) acc[j] = fmaf(wv, hwl[i*128 + kseg*8 + j], acc[j]);
      }
      float* sgG = sigbuf + (size_t)g*8192 + o*128 + kseg*8;
      #pragma unroll
      for (int j=0;j<8;j++){
        float sg = sigf(acc[j]);
        sigl[o*128 + kseg*8 + j] = sg;
        sgG[j] = sg;
      }
    }
    __syncthreads();
    // gate stats: gate = xb * sig_row * sig_col ; per-channel sum/sumsq -> scsh
    {
      int col = tid & 63, wid = tid >> 6, lane = tid & 63;
      int slot = wid >> 1, half = wid & 1;
      float s[8] = {0,0,0,0,0,0,0,0}, s2[8] = {0,0,0,0,0,0,0,0};
      const char* base = (const char*)xb + (((size_t)(g*64))*8 + slot)*1024 + col*16;
      for (int p=0;p<32;++p){
        int row = half*32 + p;
        short8v xv = *(const short8v*)(base + (size_t)row*8192);
        #pragma unroll
        for (int e=0;e<8;e++){
          int c = slot*8 + e;
          float v = bf2f((unsigned short)xv[e]) * sigl[c*128 + row] * sigl[c*128 + 64 + col];
          s[e] += v; s2[e] = fmaf(v, v, s2[e]);
        }
      }
      #pragma unroll
      for (int e=0;e<8;e++){
        #pragma unroll
        for (int off=1; off<64; off<<=1){ s[e] += __shfl_xor(s[e], off); s2[e] += __shfl_xor(s2[e], off); }
      }
      if (lane == 0){
        #pragma unroll
        for (int e=0;e<8;e++){ red[wid*16+e] = s[e]; red[wid*16+8+e] = s2[e]; }
      }
      __syncthreads();
      if (tid < 64){
        int c = tid, sl = c >> 3, e = c & 7;
        float S  = red[(sl*2)*16 + e]     + red[(sl*2+1)*16 + e];
        float S2 = red[(sl*2)*16 + 8 + e] + red[(sl*2+1)*16 + 8 + e];
        float mu = S*(1.f/4096.f);
        float var = S2*(1.f/4096.f) - mu*mu;
        float scale = rsqrtf(var + 1e-5f) * gnw[c];
        scsh[(g*64+c)*2]   = scale;
        scsh[(g*64+c)*2+1] = gnb[c] - mu*scale;
      }
    }
    return;
  }

  // ---------------- conv role (byte-identical to round 12) ----------------
  char* INL = smem;                      // 52224
  char* WL  = smem + 52224;              // 73728
  char* BRL = smem;                      // 131072 (epilogue overlay)
  char* WCL = smem + 131072;             // 16384
  float* x11l = (float*)(smem + 147456); // 64
  float* bcl  = x11l + 64;               // 64

  const int g = blockIdx.x >> 3;
  const int strip = blockIdx.x & 7;
  const int r0 = strip*8;
  const int w = tid >> 6;
  const int lane = tid & 63;
  const int l31 = lane & 31;
  const int lh  = lane >> 5;
  const int conv = w >> 3;
  const int ch2 = (w >> 2) & 1;
  const int rquad = (w >> 1) & 1;
  const int cot = w & 1;

  // stage wcat fragments (persistent): 1024 x 16B, one per thread
  gl2lds16(wcgl + (size_t)tid*16, WCL + tid*16);
  if (tid < 64){ x11l[tid] = x11[tid]; bcl[tid] = bcat[tid]; }
  // zero pad cols {0,1,66,67} of IN (once; staging never touches them)
  if (tid < 192){
    int seg = tid >> 2, pc = tid & 3;
    int colp = (pc < 2) ? pc : pc + 64;
    *(f32x4*)(INL + seg*1088 + colp*16) = (f32x4){0.f,0.f,0.f,0.f};
  }

  f32x16 acc[4];
  #pragma unroll
  for (int pt=0;pt<4;pt++)
    #pragma unroll
    for (int e=0;e<16;e++) acc[pt][e] = 0.f;

  for (int q=0;q<2;++q){
    if (q) __syncthreads();      // all reads of W/IN from q0 complete before overwrite
    // stage W chunk q (fragment-major, linear): 4608 x 16B
    #pragma unroll
    for (int k=0;k<4;k++){
      int idx = tid + k*1024;
      gl2lds16(wgl + (size_t)q*73728 + (size_t)idx*16, WL + idx*16);
    }
    if (tid < 512){
      int idx = 4096 + tid;
      gl2lds16(wgl + (size_t)q*73728 + (size_t)idx*16, WL + idx*16);
    }
    // stage IN chunk q: 48 segs (12 rows x 4 slots), 3 per wave
    #pragma unroll
    for (int i=0;i<3;++i){
      int seg = w*3 + i;
      int row = seg >> 2, slot = seg & 3;
      int rg = r0 - 2 + row;
      char* dst = INL + seg*1088 + 32;
      if ((unsigned)rg < 64u){
        const char* src = (const char*)xb + ((((size_t)(g*64+rg))*8) + q*4 + slot)*1024 + lane*16;
        gl2lds16(src, dst + lane*16);
      } else {
        *(f32x4*)(dst + lane*16) = (f32x4){0.f,0.f,0.f,0.f};
      }
    }
    __syncthreads();
    if (conv == 0) conv_q<1>(INL, WL, ch2, rquad, cot, lh, l31, lane, acc);
    else           conv_q<2>(INL, WL, ch2, rquad, cot, lh, l31, lane, acc);
  }
  __syncthreads();

  // epilogue: bias + PReLU + residual (bf16 xb, L2-hot) -> BR swizzled
  {
    const float alpha = conv ? a2p[0] : a1p[0];
    const float* bbp = conv ? bb2 : bb1;
    #pragma unroll
    for (int rq=0;rq<4;++rq){
      int co0 = cot*32 + 8*rq + 4*lh;
      float b0 = bbp[co0], b1 = bbp[co0+1], b2 = bbp[co0+2], b3 = bbp[co0+3];
      int ch0 = conv*64 + co0;
      #pragma unroll
      for (int pt=0;pt<4;++pt){
        int prow = rquad*4 + pt;
        int colg = ch2*32 + l31;
        const char* rsrc = (const char*)xb + (((size_t)(g*64 + r0 + prow))*8 + (co0>>3))*1024
                           + colg*16 + (co0&7)*2;
        ushort4 rv = *(const ushort4*)rsrc;
        float v0 = acc[pt][rq*4+0] + b0; v0 = (v0>=0.f? v0 : alpha*v0) + bf2f(rv.x);
        float v1 = acc[pt][rq*4+1] + b1; v1 = (v1>=0.f? v1 : alpha*v1) + bf2f(rv.y);
        float v2 = acc[pt][rq*4+2] + b2; v2 = (v2>=0.f? v2 : alpha*v2) + bf2f(rv.z);
        float v3 = acc[pt][rq*4+3] + b3; v3 = (v3>=0.f? v3 : alpha*v3) + bf2f(rv.w);
        int px = prow*64 + colg;
        int addr = (px*256 + ch0*2) ^ ((px & 15) << 4);
        ushort4 pk; pk.x=f2bf(v0); pk.y=f2bf(v1); pk.z=f2bf(v2); pk.w=f2bf(v3);
        *(ushort4*)(BRL + addr) = pk;
      }
    }
  }
  __syncthreads();

  // cat 1x1 conv (K=128): A from WC (LDS), B from BR; reduce to wsum2/wsum2b + x2mean
  {
    f32x16 c2[2];
    #pragma unroll
    for (int t=0;t<2;t++)
      #pragma unroll
      for (int e=0;e<16;e++) c2[t][e] = 0.f;

    #pragma unroll
    for (int kfc=0;kfc<8;++kfc){
      const char* ap = WCL + (size_t)(kfc*2 + cot)*1024 + lane*16;
      short8v A0 = *(const short8v*)(ap);
      #pragma unroll
      for (int t=0;t<2;++t){
        int px = (w>>1)*64 + t*32 + l31;
        int addr = (px*256 + kfc*32 + lh*16) ^ ((px & 15) << 4);
        short8v B = *(const short8v*)(BRL + addr);
        c2[t] = MFMA32(A0, B, c2[t]);
      }
    }
    float u0 = 0.f, u1 = 0.f;
    #pragma unroll
    for (int reg=0;reg<16;++reg){
      int o = cot*32 + (reg&3) + 8*(reg>>2) + 4*lh;
      float xw = x11l[o], bc = bcl[o];
      u0 += xw*(c2[0][reg] + bc);
      u1 += xw*(c2[1][reg] + bc);
      float sv = c2[0][reg] + c2[1][reg];
      sv += __shfl_xor(sv, 1); sv += __shfl_xor(sv, 2);
      sv += __shfl_xor(sv, 4); sv += __shfl_xor(sv, 8); sv += __shfl_xor(sv, 16);
      if (l31 == 0) atomicAdd(&x2mean[g*64 + o], sv);
    }
    u0 += __shfl_xor(u0, 32);
    u1 += __shfl_xor(u1, 32);
    if (lh == 0){
      float* wp2 = (cot ? wsum2b : wsum2) + (size_t)g*4096 + strip*512 + (w>>1)*64 + l31;
      wp2[0]  = u0;
      wp2[32] = u1;
    }
  }
}

// ---------------- K5: x21-softmax + W = wsum2+wsum2b+S+sum_c crow*ccol*xb ; out = xb*sigmoid(W) --
__global__ __launch_bounds__(256) void k_final2(const unsigned short* __restrict__ xb,
                                                const float* __restrict__ sigbuf,
                                                const float* __restrict__ scsh,
                                                const float* __restrict__ x2mean,
                                                const float* __restrict__ bcat,
                                                const float* __restrict__ wsum2,
                                                const float* __restrict__ wsum2b,
                                                float* __restrict__ out){
  int blk = blockIdx.x;                 // g*16 + chunk
  int g = blk >> 4, chunk = blk & 15;
  int tid = threadIdx.x;
  __shared__ float x21s[64];
  __shared__ float crow[64*4];
  __shared__ float ccol[64*64];
  __shared__ float Ssm;
  const float* sgb = sigbuf + (size_t)g*8192;
  if (tid < 64){
    float mean = x2mean[g*64 + tid] * (1.f/4096.f) + bcat[tid];
    float mx = mean;
    for (int s=32; s; s>>=1) mx = fmaxf(mx, __shfl_xor(mx, s));
    float e = __expf(mean - mx);
    float se = e;
    for (int s=32; s; s>>=1) se += __shfl_xor(se, s);
    x21s[tid] = e/se;
  }
  for (int idx = tid; idx < 4096; idx += 256){
    int c = idx >> 6, col = idx & 63;
    ccol[idx] = sgb[c*128 + 64 + col];
  }
  __syncthreads();
  {
    int c = tid >> 2, rr = tid & 3;
    crow[tid] = x21s[c] * scsh[(g*64+c)*2] * sgb[c*128 + chunk*4 + rr];
  }
  if (tid < 64){
    float v = x21s[tid] * scsh[(g*64+tid)*2+1];
    for (int s=32; s; s>>=1) v += __shfl_xor(v, s);
    if (tid == 0) Ssm = v;
  }
  __syncthreads();
  int px = chunk*256 + tid;
  int rr = tid >> 6, col = tid & 63;
  int row = chunk*4 + rr;
  float xv[64];
  const char* xbg = (const char*)xb + (((size_t)(g*64 + row))*8)*1024 + col*16;
  #pragma unroll
  for (int slot=0;slot<8;slot++){
    short8v v8 = *(const short8v*)(xbg + slot*1024);
    #pragma unroll
    for (int e=0;e<8;e++) xv[slot*8+e] = bf2f((unsigned short)v8[e]);
  }
  float W = wsum2[(size_t)g*4096 + px] + wsum2b[(size_t)g*4096 + px] + Ssm;
  #pragma unroll
  for (int c=0;c<64;c++){
    W = fmaf(crow[c*4+rr]*ccol[c*64+col], xv[c], W);
  }
  float s = sigf(W);
  float* op = out + (size_t)(g*64)*HWPX + px;
  #pragma unroll
  for (int c=0;c<64;c++){
    op[(size_t)c*HWPX] = xv[c] * s;
  }
}

extern "C" void kernel_launch(void* const* d_in, const int* in_sizes, int n_in,
                              void* d_out, int out_size, void* d_ws, size_t ws_size,
                              hipStream_t stream) {
  const float* x     = (const float*)d_in[0];
  const float* w_hw  = (const float*)d_in[1];
  const float* b_hw  = (const float*)d_in[2];
  const float* gn_w  = (const float*)d_in[3];
  const float* gn_b  = (const float*)d_in[4];
  const float* w_b1  = (const float*)d_in[5];
  const float* b_b1  = (const float*)d_in[6];
  const float* a_b1  = (const float*)d_in[7];
  const float* w_b2  = (const float*)d_in[8];
  const float* b_b2  = (const float*)d_in[9];
  const float* a_b2  = (const float*)d_in[10];
  const float* w_cat = (const float*)d_in[11];
  const float* b_cat = (const float*)d_in[12];

  char* ws = (char*)d_ws;
  unsigned short* wimg  = (unsigned short*)(ws + 0);          // 147456
  unsigned short* wcimg = (unsigned short*)(ws + 147456);     // 16384
  float* x11    = (float*)(ws + 163840);                      // 256
  float* x2mean = (float*)(ws + 164096);                      // 32768
  float* scsh   = (float*)(ws + 196864);                      // 65536
  float* wsum2  = (float*)(ws + 262400);                      // 2097152
  float* wsum2b = (float*)(ws + 2359552);                     // 2097152
  float* hwbuf  = (float*)(ws + 4456704);                     // 4 MiB
  float* sigb   = (float*)(ws + 8651008);                     // 4 MiB
  unsigned short* xb = (unsigned short*)(ws + 16777216);      // 64 MiB
  float* out = (float*)d_out;

  hipFuncSetAttribute(reinterpret_cast<const void*>(k_convcat),
                      hipFuncAttributeMaxDynamicSharedMemorySize, 147968);

  k_pre  <<<1092, 256, 0, stream>>>(x, w_b1, w_b2, w_cat, gn_b, xb, hwbuf, wimg, wcimg,
                                    x11, x2mean);
  k_convcat<<<1152, 1024, 147968, stream>>>(xb, (const char*)wimg, (const char*)wcimg,
                                            hwbuf, w_hw, b_hw, sigb, gn_w, gn_b,
                                            b_b1, b_b2, a_b1, a_b2, b_cat, x11,
                                            wsum2, wsum2b, x2mean, scsh);
  k_final2<<<2048, 256, 0, stream>>>(xb, sigb, scsh, x2mean, b_cat, wsum2, wsum2b, out);
}

// Round 17
// 264.310 us; speedup vs baseline: 1.0342x; 1.0342x over previous
//
#include <hip/hip_runtime.h>
#include <hip/hip_bf16.h>

#define HWPX 4096

typedef __attribute__((ext_vector_type(8))) short short8v;
typedef __attribute__((ext_vector_type(4))) float f32x4;
typedef __attribute__((ext_vector_type(16))) float f32x16;
#define MFMA32(a,b,c) __builtin_amdgcn_mfma_f32_32x32x16_bf16(a,b,c,0,0,0)

__device__ __forceinline__ float sigf(float x){ return 1.0f/(1.0f+__expf(-x)); }
__device__ __forceinline__ unsigned short f2bf(float f){
  __hip_bfloat16 h = __float2bfloat16(f);
  unsigned short u; __builtin_memcpy(&u, &h, sizeof(u)); return u;
}
__device__ __forceinline__ float bf2f(unsigned short u){
  return __uint_as_float(((unsigned)u)<<16);
}
__device__ __forceinline__ void gl2lds16(const void* g, void* l){
  __builtin_amdgcn_global_load_lds((const __attribute__((address_space(1))) void*)g,
                                   (__attribute__((address_space(3))) void*)l, 16, 0, 0);
}

// ---------------- K1: merged prep (round-5 weight layout + x11) / rc / x2mean zero ----------------
__global__ __launch_bounds__(256) void k_pre(const float* __restrict__ x,
                                             const float* __restrict__ wb1,
                                             const float* __restrict__ wb2,
                                             const float* __restrict__ wcat,
                                             const float* __restrict__ gnb,
                                             unsigned short* __restrict__ xb,
                                             float* __restrict__ hwbuf,
                                             unsigned short* __restrict__ wimg,
                                             unsigned short* __restrict__ wcimg,
                                             float* __restrict__ x11,
                                             float* __restrict__ x2mean){
  int bid = blockIdx.x, tid = threadIdx.x;
  if (bid >= 1088){
    int idx = (bid - 1088)*2048 + tid*8;
    f32x4 z = {0.f,0.f,0.f,0.f};
    *(f32x4*)(x2mean + idx) = z;
    *(f32x4*)(x2mean + idx + 4) = z;
    return;
  }
  if (bid >= 1024){
    int bid2 = bid - 1024;
    for (int idx = bid2*256 + tid; idx < 73728; idx += 64*256){
      int f = idx >> 9, r = idx & 511, lane = r >> 3, j = r & 7;
      int qc = f / 36, rem = f % 36, tap = rem >> 2, kc = rem & 3;
      int q = qc >> 1, conv = qc & 1, kf = kc >> 1, cot = kc & 1;
      int co = cot*32 + (lane & 31);
      int ci = q*32 + kf*16 + (lane >> 5)*8 + j;
      const float* src = conv ? wb2 : wb1;
      wimg[idx] = f2bf(src[(co*64 + ci)*9 + tap]);
    }
    if (bid2 == 0){
      for (int idx = tid; idx < 8192; idx += 256){
        int f = idx >> 9, r = idx & 511, lane = r >> 3, j = r & 7;
        int kfc = f >> 1, cot = f & 1;
        int o = cot*32 + (lane & 31);
        int ch = kfc*16 + (lane >> 5)*8 + j;
        wcimg[idx] = f2bf(wcat[o*128 + ch]);
      }
      if (tid < 64){
        float g = gnb[tid];
        float m = g;
        for (int s=32; s; s>>=1) m = fmaxf(m, __shfl_xor(m, s));
        float e = __expf(g-m);
        float se = e;
        for (int s=32; s; s>>=1) se += __shfl_xor(se, s);
        x11[tid] = e/se;
      }
    }
    return;
  }
  // ---- rc ----
  int g = bid >> 3, slot = bid & 7;
  int col = tid & 63, wid = tid >> 6;
  __shared__ float rsm[8*64];
  __shared__ float csm[4*8*64];
  float colacc[8] = {0,0,0,0,0,0,0,0};
  const float* xbase = x + ((size_t)(g*64 + slot*8))*HWPX;
  for (int p=0;p<16;++p){
    int r = wid + 4*p;
    const float* src = xbase + r*64 + col;
    float v[8];
    #pragma unroll
    for (int e=0;e<8;e++) v[e] = src[(size_t)e*HWPX];
    unsigned pk[4];
    #pragma unroll
    for (int j=0;j<4;j++) pk[j] = (unsigned)f2bf(v[2*j]) | ((unsigned)f2bf(v[2*j+1])<<16);
    f32x4 st; __builtin_memcpy(&st, pk, 16);
    *(f32x4*)((char*)xb + (((size_t)(g*64+r))*8 + slot)*1024 + col*16) = st;
    #pragma unroll
    for (int e=0;e<8;e++){
      float s = v[e];
      s += __shfl_xor(s,1); s += __shfl_xor(s,2); s += __shfl_xor(s,4);
      s += __shfl_xor(s,8); s += __shfl_xor(s,16); s += __shfl_xor(s,32);
      if ((tid&63)==0) rsm[e*64+r] = s;
      colacc[e] += v[e];
    }
  }
  #pragma unroll
  for (int e=0;e<8;e++) csm[(wid*8+e)*64+col] = colacc[e];
  __syncthreads();
  float* hb = hwbuf + ((size_t)(g*64 + slot*8))*128;
  for (int idx=tid; idx<512; idx+=256){
    int e = idx>>6, r = idx&63;
    hb[e*128 + r] = rsm[e*64+r] * (1.0f/64.0f);
  }
  for (int idx=tid; idx<512; idx+=256){
    int e = idx>>6, c2 = idx&63;
    float s = csm[(0*8+e)*64+c2] + csm[(1*8+e)*64+c2] + csm[(2*8+e)*64+c2] + csm[(3*8+e)*64+c2];
    hb[e*128 + 64 + c2] = s * (1.0f/64.0f);
  }
}

// ---------------- K2: hw = sigmoid(w_hw @ hw + b_hw) -> sigbuf[bg][o][128] ----------------
__global__ __launch_bounds__(256) void k_hwmm(const float* hwbuf, const float* whw,
                                              const float* bhw, float* sigbuf){
  int g = blockIdx.x;
  __shared__ float hl[64*128];
  int tid = threadIdx.x;
  const float* src = hwbuf + (size_t)g*8192;
  for (int i = tid; i < 2048; i += 256) ((float4*)hl)[i] = ((const float4*)src)[i];
  __syncthreads();
  int p  = tid & 127;
  int o0 = (tid >> 7) * 32;
  float acc[32];
  #pragma unroll
  for (int k=0;k<32;k++) acc[k] = bhw[o0+k];
  for (int i=0;i<64;i++){
    float v = hl[i*128+p];
    #pragma unroll
    for (int k=0;k<32;k++) acc[k] = fmaf(whw[(o0+k)*64+i], v, acc[k]);
  }
  float* dst = sigbuf + (size_t)g*8192;
  #pragma unroll
  for (int k=0;k<32;k++) dst[(o0+k)*128+p] = sigf(acc[k]);
}

// ---------------- conv compute (per q): dx-outer B-register reuse, A from LDS, cot-split ---------
template<int DIL>
__device__ __forceinline__ void conv_q(const char* INL, const char* WL,
                                       int ch2, int rquad, int cot, int lh, int l31, int lane,
                                       f32x16 (&acc)[4]){
  constexpr int conv = DIL - 1;
  constexpr int NROW = 4 + 2*DIL;
  #pragma unroll
  for (int kf=0; kf<2; ++kf){
    const char* ibase = INL + (kf*2 + lh)*1088 + (ch2*32 + 2 + l31)*16
                        + (rquad*4 + 2 - DIL)*4352;
    #pragma unroll
    for (int dxx=0; dxx<3; ++dxx){
      const char* ib = ibase + ((dxx-1)*DIL)*16;
      short8v Brow[NROW];
      #pragma unroll
      for (int i=0;i<NROW;++i) Brow[i] = *(const short8v*)(ib + i*4352);
      #pragma unroll
      for (int dyp=0;dyp<3;++dyp){
        int tap = dyp*3 + dxx;
        const char* wp = WL + (size_t)(((conv*9+tap)*4 + kf*2 + cot)*1024) + lane*16;
        short8v A0 = *(const short8v*)(wp);
        #pragma unroll
        for (int pt=0;pt<4;++pt)
          acc[pt] = MFMA32(A0, Brow[pt + dyp*DIL], acc[pt]);
      }
    }
  }
}

// ---------------- K4: conv blocks (0..1023, r12-exact) + gate2 blocks (1024..1279) ---------------
// conv: 16 waves, round-5 staging, dx-outer B-reuse; LDS 147968, 1 block/CU.
// gate2 role: 4 x 256-thread groups, each = one (g,slot) stat unit; uses dynamic smem.
__global__ __launch_bounds__(1024) void k_convcat(const unsigned short* __restrict__ xb,
                                                  const char* __restrict__ wgl,
                                                  const char* __restrict__ wcgl,
                                                  const float* __restrict__ sigbuf,
                                                  const float* __restrict__ gnw,
                                                  const float* __restrict__ gnb,
                                                  const float* __restrict__ bb1,
                                                  const float* __restrict__ bb2,
                                                  const float* __restrict__ a1p,
                                                  const float* __restrict__ a2p,
                                                  const float* __restrict__ bcat,
                                                  const float* __restrict__ x11,
                                                  float* __restrict__ wsum2,
                                                  float* __restrict__ wsum2b,
                                                  float* __restrict__ x2mean,
                                                  float* __restrict__ scsh){
  extern __shared__ char smem[];
  const int tid = threadIdx.x;

  if (blockIdx.x >= 1024){
    // ---------------- gate2 role: GroupNorm gate statistics ----------------
    int grp = tid >> 8;                 // 0..3
    int tl  = tid & 255;
    int unit = (blockIdx.x - 1024)*4 + grp;   // 0..1023
    int g = unit >> 3, slot = unit & 7;
    int col = tl & 63, wq = tl >> 6, lane = tl & 63;
    float* srm = (float*)smem + grp*1088;
    float* scm = srm + 512;
    float* red = scm + 512;
    for (int idx = tl; idx < 1024; idx += 256){
      int e = idx >> 7, k = idx & 127;
      float v = sigbuf[(size_t)g*8192 + (size_t)(slot*8+e)*128 + k];
      if (k < 64) srm[e*64+k] = v; else scm[e*64+k-64] = v;
    }
    __syncthreads();
    float s[8] = {0,0,0,0,0,0,0,0}, s2[8] = {0,0,0,0,0,0,0,0};
    const char* base = (const char*)xb + (((size_t)(g*64))*8 + slot)*1024;
    for (int p=0;p<16;++p){
      int row = wq*16 + p;
      short8v xv = *(const short8v*)(base + (size_t)row*8192 + col*16);
      #pragma unroll
      for (int e=0;e<8;e++){
        float v = bf2f((unsigned short)xv[e]) * srm[e*64+row] * scm[e*64+col];
        s[e] += v; s2[e] = fmaf(v, v, s2[e]);
      }
    }
    #pragma unroll
    for (int e=0;e<8;e++){
      #pragma unroll
      for (int off=1; off<64; off<<=1){ s[e] += __shfl_xor(s[e], off); s2[e] += __shfl_xor(s2[e], off); }
    }
    if (lane == 0){
      #pragma unroll
      for (int e=0;e<8;e++){ red[wq*16+e] = s[e]; red[wq*16+8+e] = s2[e]; }
    }
    __syncthreads();
    if (tl < 8){
      float S  = red[tl]   + red[16+tl] + red[32+tl] + red[48+tl];
      float S2 = red[8+tl] + red[24+tl] + red[40+tl] + red[56+tl];
      float mu = S*(1.f/4096.f);
      float var = S2*(1.f/4096.f) - mu*mu;
      int c = slot*8 + tl;
      float scale = rsqrtf(var + 1e-5f) * gnw[c];
      scsh[(g*64+c)*2]   = scale;
      scsh[(g*64+c)*2+1] = gnb[c] - mu*scale;
    }
    return;
  }

  // ---------------- conv role (byte-identical to round 12) ----------------
  char* INL = smem;                      // 52224
  char* WL  = smem + 52224;              // 73728
  char* BRL = smem;                      // 131072 (epilogue overlay)
  char* WCL = smem + 131072;             // 16384
  float* x11l = (float*)(smem + 147456); // 64
  float* bcl  = x11l + 64;               // 64

  const int g = blockIdx.x >> 3;
  const int strip = blockIdx.x & 7;
  const int r0 = strip*8;
  const int w = tid >> 6;
  const int lane = tid & 63;
  const int l31 = lane & 31;
  const int lh  = lane >> 5;
  const int conv = w >> 3;
  const int ch2 = (w >> 2) & 1;
  const int rquad = (w >> 1) & 1;
  const int cot = w & 1;

  // stage wcat fragments (persistent): 1024 x 16B, one per thread
  gl2lds16(wcgl + (size_t)tid*16, WCL + tid*16);
  if (tid < 64){ x11l[tid] = x11[tid]; bcl[tid] = bcat[tid]; }
  // zero pad cols {0,1,66,67} of IN (once; staging never touches them)
  if (tid < 192){
    int seg = tid >> 2, pc = tid & 3;
    int colp = (pc < 2) ? pc : pc + 64;
    *(f32x4*)(INL + seg*1088 + colp*16) = (f32x4){0.f,0.f,0.f,0.f};
  }

  f32x16 acc[4];
  #pragma unroll
  for (int pt=0;pt<4;pt++)
    #pragma unroll
    for (int e=0;e<16;e++) acc[pt][e] = 0.f;

  for (int q=0;q<2;++q){
    if (q) __syncthreads();      // all reads of W/IN from q0 complete before overwrite
    // stage W chunk q (fragment-major, linear): 4608 x 16B
    #pragma unroll
    for (int k=0;k<4;k++){
      int idx = tid + k*1024;
      gl2lds16(wgl + (size_t)q*73728 + (size_t)idx*16, WL + idx*16);
    }
    if (tid < 512){
      int idx = 4096 + tid;
      gl2lds16(wgl + (size_t)q*73728 + (size_t)idx*16, WL + idx*16);
    }
    // stage IN chunk q: 48 segs (12 rows x 4 slots), 3 per wave
    #pragma unroll
    for (int i=0;i<3;++i){
      int seg = w*3 + i;
      int row = seg >> 2, slot = seg & 3;
      int rg = r0 - 2 + row;
      char* dst = INL + seg*1088 + 32;
      if ((unsigned)rg < 64u){
        const char* src = (const char*)xb + ((((size_t)(g*64+rg))*8) + q*4 + slot)*1024 + lane*16;
        gl2lds16(src, dst + lane*16);
      } else {
        *(f32x4*)(dst + lane*16) = (f32x4){0.f,0.f,0.f,0.f};
      }
    }
    __syncthreads();
    if (conv == 0) conv_q<1>(INL, WL, ch2, rquad, cot, lh, l31, lane, acc);
    else           conv_q<2>(INL, WL, ch2, rquad, cot, lh, l31, lane, acc);
  }
  __syncthreads();

  // epilogue: bias + PReLU + residual (bf16 xb, L2-hot) -> BR swizzled
  {
    const float alpha = conv ? a2p[0] : a1p[0];
    const float* bbp = conv ? bb2 : bb1;
    #pragma unroll
    for (int rq=0;rq<4;++rq){
      int co0 = cot*32 + 8*rq + 4*lh;
      float b0 = bbp[co0], b1 = bbp[co0+1], b2 = bbp[co0+2], b3 = bbp[co0+3];
      int ch0 = conv*64 + co0;
      #pragma unroll
      for (int pt=0;pt<4;++pt){
        int prow = rquad*4 + pt;
        int colg = ch2*32 + l31;
        const char* rsrc = (const char*)xb + (((size_t)(g*64 + r0 + prow))*8 + (co0>>3))*1024
                           + colg*16 + (co0&7)*2;
        ushort4 rv = *(const ushort4*)rsrc;
        float v0 = acc[pt][rq*4+0] + b0; v0 = (v0>=0.f? v0 : alpha*v0) + bf2f(rv.x);
        float v1 = acc[pt][rq*4+1] + b1; v1 = (v1>=0.f? v1 : alpha*v1) + bf2f(rv.y);
        float v2 = acc[pt][rq*4+2] + b2; v2 = (v2>=0.f? v2 : alpha*v2) + bf2f(rv.z);
        float v3 = acc[pt][rq*4+3] + b3; v3 = (v3>=0.f? v3 : alpha*v3) + bf2f(rv.w);
        int px = prow*64 + colg;
        int addr = (px*256 + ch0*2) ^ ((px & 15) << 4);
        ushort4 pk; pk.x=f2bf(v0); pk.y=f2bf(v1); pk.z=f2bf(v2); pk.w=f2bf(v3);
        *(ushort4*)(BRL + addr) = pk;
      }
    }
  }
  __syncthreads();

  // cat 1x1 conv (K=128): A from WC (LDS), B from BR; reduce to wsum2/wsum2b + x2mean
  {
    f32x16 c2[2];
    #pragma unroll
    for (int t=0;t<2;t++)
      #pragma unroll
      for (int e=0;e<16;e++) c2[t][e] = 0.f;

    #pragma unroll
    for (int kfc=0;kfc<8;++kfc){
      const char* ap = WCL + (size_t)(kfc*2 + cot)*1024 + lane*16;
      short8v A0 = *(const short8v*)(ap);
      #pragma unroll
      for (int t=0;t<2;++t){
        int px = (w>>1)*64 + t*32 + l31;
        int addr = (px*256 + kfc*32 + lh*16) ^ ((px & 15) << 4);
        short8v B = *(const short8v*)(BRL + addr);
        c2[t] = MFMA32(A0, B, c2[t]);
      }
    }
    float u0 = 0.f, u1 = 0.f;
    #pragma unroll
    for (int reg=0;reg<16;++reg){
      int o = cot*32 + (reg&3) + 8*(reg>>2) + 4*lh;
      float xw = x11l[o], bc = bcl[o];
      u0 += xw*(c2[0][reg] + bc);
      u1 += xw*(c2[1][reg] + bc);
      float sv = c2[0][reg] + c2[1][reg];
      sv += __shfl_xor(sv, 1); sv += __shfl_xor(sv, 2);
      sv += __shfl_xor(sv, 4); sv += __shfl_xor(sv, 8); sv += __shfl_xor(sv, 16);
      if (l31 == 0) atomicAdd(&x2mean[g*64 + o], sv);
    }
    u0 += __shfl_xor(u0, 32);
    u1 += __shfl_xor(u1, 32);
    if (lh == 0){
      float* wp2 = (cot ? wsum2b : wsum2) + (size_t)g*4096 + strip*512 + (w>>1)*64 + l31;
      wp2[0]  = u0;
      wp2[32] = u1;
    }
  }
}

// ---------------- K5: x21-softmax + W = wsum2+wsum2b+S+sum_c crow*ccol*xb ; out = xb*sigmoid(W) --
__global__ __launch_bounds__(256) void k_final2(const unsigned short* __restrict__ xb,
                                                const float* __restrict__ sigbuf,
                                                const float* __restrict__ scsh,
                                                const float* __restrict__ x2mean,
                                                const float* __restrict__ bcat,
                                                const float* __restrict__ wsum2,
                                                const float* __restrict__ wsum2b,
                                                float* __restrict__ out){
  int blk = blockIdx.x;                 // g*16 + chunk
  int g = blk >> 4, chunk = blk & 15;
  int tid = threadIdx.x;
  __shared__ float x21s[64];
  __shared__ float crow[64*4];
  __shared__ float ccol[64*64];
  __shared__ float Ssm;
  const float* sgb = sigbuf + (size_t)g*8192;
  if (tid < 64){
    float mean = x2mean[g*64 + tid] * (1.f/4096.f) + bcat[tid];
    float mx = mean;
    for (int s=32; s; s>>=1) mx = fmaxf(mx, __shfl_xor(mx, s));
    float e = __expf(mean - mx);
    float se = e;
    for (int s=32; s; s>>=1) se += __shfl_xor(se, s);
    x21s[tid] = e/se;
  }
  for (int idx = tid; idx < 4096; idx += 256){
    int c = idx >> 6, col = idx & 63;
    ccol[idx] = sgb[c*128 + 64 + col];
  }
  __syncthreads();
  {
    int c = tid >> 2, rr = tid & 3;
    crow[tid] = x21s[c] * scsh[(g*64+c)*2] * sgb[c*128 + chunk*4 + rr];
  }
  if (tid < 64){
    float v = x21s[tid] * scsh[(g*64+tid)*2+1];
    for (int s=32; s; s>>=1) v += __shfl_xor(v, s);
    if (tid == 0) Ssm = v;
  }
  __syncthreads();
  int px = chunk*256 + tid;
  int rr = tid >> 6, col = tid & 63;
  int row = chunk*4 + rr;
  float xv[64];
  const char* xbg = (const char*)xb + (((size_t)(g*64 + row))*8)*1024 + col*16;
  #pragma unroll
  for (int slot=0;slot<8;slot++){
    short8v v8 = *(const short8v*)(xbg + slot*1024);
    #pragma unroll
    for (int e=0;e<8;e++) xv[slot*8+e] = bf2f((unsigned short)v8[e]);
  }
  float W = wsum2[(size_t)g*4096 + px] + wsum2b[(size_t)g*4096 + px] + Ssm;
  #pragma unroll
  for (int c=0;c<64;c++){
    W = fmaf(crow[c*4+rr]*ccol[c*64+col], xv[c], W);
  }
  float s = sigf(W);
  float* op = out + (size_t)(g*64)*HWPX + px;
  #pragma unroll
  for (int c=0;c<64;c++){
    op[(size_t)c*HWPX] = xv[c] * s;
  }
}

extern "C" void kernel_launch(void* const* d_in, const int* in_sizes, int n_in,
                              void* d_out, int out_size, void* d_ws, size_t ws_size,
                              hipStream_t stream) {
  const float* x     = (const float*)d_in[0];
  const float* w_hw  = (const float*)d_in[1];
  const float* b_hw  = (const float*)d_in[2];
  const float* gn_w  = (const float*)d_in[3];
  const float* gn_b  = (const float*)d_in[4];
  const float* w_b1  = (const float*)d_in[5];
  const float* b_b1  = (const float*)d_in[6];
  const float* a_b1  = (const float*)d_in[7];
  const float* w_b2  = (const float*)d_in[8];
  const float* b_b2  = (const float*)d_in[9];
  const float* a_b2  = (const float*)d_in[10];
  const float* w_cat = (const float*)d_in[11];
  const float* b_cat = (const float*)d_in[12];

  char* ws = (char*)d_ws;
  unsigned short* wimg  = (unsigned short*)(ws + 0);          // 147456
  unsigned short* wcimg = (unsigned short*)(ws + 147456);     // 16384
  float* x11    = (float*)(ws + 163840);                      // 256
  float* x2mean = (float*)(ws + 164096);                      // 32768
  float* scsh   = (float*)(ws + 196864);                      // 65536
  float* wsum2  = (float*)(ws + 262400);                      // 2097152
  float* wsum2b = (float*)(ws + 2359552);                     // 2097152
  float* hwbuf  = (float*)(ws + 4456704);                     // 4 MiB
  float* sigb   = (float*)(ws + 8651008);                     // 4 MiB
  unsigned short* xb = (unsigned short*)(ws + 16777216);      // 64 MiB
  float* out = (float*)d_out;

  hipFuncSetAttribute(reinterpret_cast<const void*>(k_convcat),
                      hipFuncAttributeMaxDynamicSharedMemorySize, 147968);

  k_pre  <<<1092, 256, 0, stream>>>(x, w_b1, w_b2, w_cat, gn_b, xb, hwbuf, wimg, wcimg,
                                    x11, x2mean);
  k_hwmm <<<128,  256, 0, stream>>>(hwbuf, w_hw, b_hw, sigb);
  k_convcat<<<1280, 1024, 147968, stream>>>(xb, (const char*)wimg, (const char*)wcimg,
                                            sigb, gn_w, gn_b, b_b1, b_b2, a_b1, a_b2,
                                            b_cat, x11, wsum2, wsum2b, x2mean, scsh);
  k_final2<<<2048, 256, 0, stream>>>(xb, sigb, scsh, x2mean, b_cat, wsum2, wsum2b, out);
}

// Round 18
// 250.712 us; speedup vs baseline: 1.0903x; 1.0542x over previous
//
#include <hip/hip_runtime.h>
#include <hip/hip_bf16.h>

#define HWPX 4096

typedef __attribute__((ext_vector_type(8))) short short8v;
typedef __attribute__((ext_vector_type(4))) float f32x4;
typedef __attribute__((ext_vector_type(16))) float f32x16;
#define MFMA32(a,b,c) __builtin_amdgcn_mfma_f32_32x32x16_bf16(a,b,c,0,0,0)

__device__ __forceinline__ float sigf(float x){ return 1.0f/(1.0f+__expf(-x)); }
__device__ __forceinline__ unsigned short f2bf(float f){
  __hip_bfloat16 h = __float2bfloat16(f);
  unsigned short u; __builtin_memcpy(&u, &h, sizeof(u)); return u;
}
__device__ __forceinline__ float bf2f(unsigned short u){
  return __uint_as_float(((unsigned)u)<<16);
}
__device__ __forceinline__ void gl2lds16(const void* g, void* l){
  __builtin_amdgcn_global_load_lds((const __attribute__((address_space(1))) void*)g,
                                   (__attribute__((address_space(3))) void*)l, 16, 0, 0);
}

// ---------------- K1: merged prep (round-5 weight layout + x11) / rc / x2mean zero ----------------
__global__ __launch_bounds__(256) void k_pre(const float* __restrict__ x,
                                             const float* __restrict__ wb1,
                                             const float* __restrict__ wb2,
                                             const float* __restrict__ wcat,
                                             const float* __restrict__ gnb,
                                             unsigned short* __restrict__ xb,
                                             float* __restrict__ hwbuf,
                                             unsigned short* __restrict__ wimg,
                                             unsigned short* __restrict__ wcimg,
                                             float* __restrict__ x11,
                                             float* __restrict__ x2mean){
  int bid = blockIdx.x, tid = threadIdx.x;
  if (bid >= 1088){
    int idx = (bid - 1088)*2048 + tid*8;
    f32x4 z = {0.f,0.f,0.f,0.f};
    *(f32x4*)(x2mean + idx) = z;
    *(f32x4*)(x2mean + idx + 4) = z;
    return;
  }
  if (bid >= 1024){
    int bid2 = bid - 1024;
    for (int idx = bid2*256 + tid; idx < 73728; idx += 64*256){
      int f = idx >> 9, r = idx & 511, lane = r >> 3, j = r & 7;
      int qc = f / 36, rem = f % 36, tap = rem >> 2, kc = rem & 3;
      int q = qc >> 1, conv = qc & 1, kf = kc >> 1, cot = kc & 1;
      int co = cot*32 + (lane & 31);
      int ci = q*32 + kf*16 + (lane >> 5)*8 + j;
      const float* src = conv ? wb2 : wb1;
      wimg[idx] = f2bf(src[(co*64 + ci)*9 + tap]);
    }
    if (bid2 == 0){
      for (int idx = tid; idx < 8192; idx += 256){
        int f = idx >> 9, r = idx & 511, lane = r >> 3, j = r & 7;
        int kfc = f >> 1, cot = f & 1;
        int o = cot*32 + (lane & 31);
        int ch = kfc*16 + (lane >> 5)*8 + j;
        wcimg[idx] = f2bf(wcat[o*128 + ch]);
      }
      if (tid < 64){
        float g = gnb[tid];
        float m = g;
        for (int s=32; s; s>>=1) m = fmaxf(m, __shfl_xor(m, s));
        float e = __expf(g-m);
        float se = e;
        for (int s=32; s; s>>=1) se += __shfl_xor(se, s);
        x11[tid] = e/se;
      }
    }
    return;
  }
  // ---- rc ----
  int g = bid >> 3, slot = bid & 7;
  int col = tid & 63, wid = tid >> 6;
  __shared__ float rsm[8*64];
  __shared__ float csm[4*8*64];
  float colacc[8] = {0,0,0,0,0,0,0,0};
  const float* xbase = x + ((size_t)(g*64 + slot*8))*HWPX;
  for (int p=0;p<16;++p){
    int r = wid + 4*p;
    const float* src = xbase + r*64 + col;
    float v[8];
    #pragma unroll
    for (int e=0;e<8;e++) v[e] = src[(size_t)e*HWPX];
    unsigned pk[4];
    #pragma unroll
    for (int j=0;j<4;j++) pk[j] = (unsigned)f2bf(v[2*j]) | ((unsigned)f2bf(v[2*j+1])<<16);
    f32x4 st; __builtin_memcpy(&st, pk, 16);
    *(f32x4*)((char*)xb + (((size_t)(g*64+r))*8 + slot)*1024 + col*16) = st;
    #pragma unroll
    for (int e=0;e<8;e++){
      float s = v[e];
      s += __shfl_xor(s,1); s += __shfl_xor(s,2); s += __shfl_xor(s,4);
      s += __shfl_xor(s,8); s += __shfl_xor(s,16); s += __shfl_xor(s,32);
      if ((tid&63)==0) rsm[e*64+r] = s;
      colacc[e] += v[e];
    }
  }
  #pragma unroll
  for (int e=0;e<8;e++) csm[(wid*8+e)*64+col] = colacc[e];
  __syncthreads();
  float* hb = hwbuf + ((size_t)(g*64 + slot*8))*128;
  for (int idx=tid; idx<512; idx+=256){
    int e = idx>>6, r = idx&63;
    hb[e*128 + r] = rsm[e*64+r] * (1.0f/64.0f);
  }
  for (int idx=tid; idx<512; idx+=256){
    int e = idx>>6, c2 = idx&63;
    float s = csm[(0*8+e)*64+c2] + csm[(1*8+e)*64+c2] + csm[(2*8+e)*64+c2] + csm[(3*8+e)*64+c2];
    hb[e*128 + 64 + c2] = s * (1.0f/64.0f);
  }
}

// ---------------- conv compute (per q): dx-outer B-register reuse, A from LDS, cot-split ---------
template<int DIL>
__device__ __forceinline__ void conv_q(const char* INL, const char* WL,
                                       int ch2, int rquad, int cot, int lh, int l31, int lane,
                                       f32x16 (&acc)[4]){
  constexpr int conv = DIL - 1;
  constexpr int NROW = 4 + 2*DIL;
  #pragma unroll
  for (int kf=0; kf<2; ++kf){
    const char* ibase = INL + (kf*2 + lh)*1088 + (ch2*32 + 2 + l31)*16
                        + (rquad*4 + 2 - DIL)*4352;
    #pragma unroll
    for (int dxx=0; dxx<3; ++dxx){
      const char* ib = ibase + ((dxx-1)*DIL)*16;
      short8v Brow[NROW];
      #pragma unroll
      for (int i=0;i<NROW;++i) Brow[i] = *(const short8v*)(ib + i*4352);
      #pragma unroll
      for (int dyp=0;dyp<3;++dyp){
        int tap = dyp*3 + dxx;
        const char* wp = WL + (size_t)(((conv*9+tap)*4 + kf*2 + cot)*1024) + lane*16;
        short8v A0 = *(const short8v*)(wp);
        #pragma unroll
        for (int pt=0;pt<4;++pt)
          acc[pt] = MFMA32(A0, Brow[pt + dyp*DIL], acc[pt]);
      }
    }
  }
}

// ---------------- K4: conv blocks (0..1023, r12-exact) + gate2' blocks (1024..1151) --------------
// conv: 16 waves, round-5 staging, dx-outer B-reuse; LDS 147968, 1 block/CU.
// gate2' role: one g per 1024-thr block: hwmm (conflict-free: broadcast hwl, wl stride-65,
//   sigl stride-130) + sigmoid -> sigl/sigbuf, then GroupNorm gate stats -> scsh.
__global__ __launch_bounds__(1024) void k_convcat(const unsigned short* __restrict__ xb,
                                                  const char* __restrict__ wgl,
                                                  const char* __restrict__ wcgl,
                                                  const float* __restrict__ hwbuf,
                                                  const float* __restrict__ whw,
                                                  const float* __restrict__ bhw,
                                                  float* __restrict__ sigbuf,
                                                  const float* __restrict__ gnw,
                                                  const float* __restrict__ gnb,
                                                  const float* __restrict__ bb1,
                                                  const float* __restrict__ bb2,
                                                  const float* __restrict__ a1p,
                                                  const float* __restrict__ a2p,
                                                  const float* __restrict__ bcat,
                                                  const float* __restrict__ x11,
                                                  float* __restrict__ wsum2,
                                                  float* __restrict__ wsum2b,
                                                  float* __restrict__ x2mean,
                                                  float* __restrict__ scsh){
  extern __shared__ char smem[];
  const int tid = threadIdx.x;

  if (blockIdx.x >= 1024){
    // ---------------- gate2' role ----------------
    int g = blockIdx.x - 1024;             // 0..127
    float* hwl  = (float*)smem;            // 8192 f   [c][128] linear
    float* sigl = (float*)smem + 8192;     // 8320 f   [c][130] padded
    float* red  = (float*)smem + 16512;    // 256 f
    float* wl   = (float*)smem + 16768;    // 4160 f   [o][65] padded
    // stage hwbuf[g] (32KB) + w_hw (padded)
    {
      const f32x4* src = (const f32x4*)(hwbuf + (size_t)g*8192);
      f32x4* dst = (f32x4*)hwl;
      dst[tid*2]   = src[tid*2];
      dst[tid*2+1] = src[tid*2+1];
      for (int idx = tid; idx < 4096; idx += 1024){
        int o = idx >> 6, i = idx & 63;
        wl[o*65 + i] = whw[idx];
      }
    }
    __syncthreads();
    // matmul: sig = sigmoid(whw @ hw + bhw); o = lane (broadcast hwl, 2-way wl)
    {
      int o = tid & 63, seg = tid >> 6;    // seg 0..15
      float acc[8];
      float bv = bhw[o];
      #pragma unroll
      for (int j=0;j<8;j++) acc[j] = bv;
      for (int i=0;i<64;++i){
        float wv = wl[o*65 + i];
        const float* hp = &hwl[i*128 + seg*8];
        #pragma unroll
        for (int j=0;j<8;j++) acc[j] = fmaf(wv, hp[j], acc[j]);
      }
      float* sgG = sigbuf + (size_t)g*8192 + o*128 + seg*8;
      #pragma unroll
      for (int j=0;j<8;j++){
        float sg = sigf(acc[j]);
        sigl[o*130 + seg*8 + j] = sg;
        sgG[j] = sg;
      }
    }
    __syncthreads();
    // gate stats: gate = xb * sig_row * sig_col ; per-channel sum/sumsq -> scsh
    {
      int col = tid & 63, wid = tid >> 6, lane = tid & 63;
      int slot = wid >> 1, half = wid & 1;
      float s[8] = {0,0,0,0,0,0,0,0}, s2[8] = {0,0,0,0,0,0,0,0};
      const char* base = (const char*)xb + (((size_t)(g*64))*8 + slot)*1024 + col*16;
      for (int p=0;p<32;++p){
        int row = half*32 + p;
        short8v xv = *(const short8v*)(base + (size_t)row*8192);
        #pragma unroll
        for (int e=0;e<8;e++){
          int c = slot*8 + e;
          float v = bf2f((unsigned short)xv[e]) * sigl[c*130 + row] * sigl[c*130 + 64 + col];
          s[e] += v; s2[e] = fmaf(v, v, s2[e]);
        }
      }
      #pragma unroll
      for (int e=0;e<8;e++){
        #pragma unroll
        for (int off=1; off<64; off<<=1){ s[e] += __shfl_xor(s[e], off); s2[e] += __shfl_xor(s2[e], off); }
      }
      if (lane == 0){
        #pragma unroll
        for (int e=0;e<8;e++){ red[wid*16+e] = s[e]; red[wid*16+8+e] = s2[e]; }
      }
      __syncthreads();
      if (tid < 64){
        int c = tid, sl = c >> 3, e = c & 7;
        float S  = red[(sl*2)*16 + e]     + red[(sl*2+1)*16 + e];
        float S2 = red[(sl*2)*16 + 8 + e] + red[(sl*2+1)*16 + 8 + e];
        float mu = S*(1.f/4096.f);
        float var = S2*(1.f/4096.f) - mu*mu;
        float scale = rsqrtf(var + 1e-5f) * gnw[c];
        scsh[(g*64+c)*2]   = scale;
        scsh[(g*64+c)*2+1] = gnb[c] - mu*scale;
      }
    }
    return;
  }

  // ---------------- conv role (byte-identical to round 12) ----------------
  char* INL = smem;                      // 52224
  char* WL  = smem + 52224;              // 73728
  char* BRL = smem;                      // 131072 (epilogue overlay)
  char* WCL = smem + 131072;             // 16384
  float* x11l = (float*)(smem + 147456); // 64
  float* bcl  = x11l + 64;               // 64

  const int g = blockIdx.x >> 3;
  const int strip = blockIdx.x & 7;
  const int r0 = strip*8;
  const int w = tid >> 6;
  const int lane = tid & 63;
  const int l31 = lane & 31;
  const int lh  = lane >> 5;
  const int conv = w >> 3;
  const int ch2 = (w >> 2) & 1;
  const int rquad = (w >> 1) & 1;
  const int cot = w & 1;

  // stage wcat fragments (persistent): 1024 x 16B, one per thread
  gl2lds16(wcgl + (size_t)tid*16, WCL + tid*16);
  if (tid < 64){ x11l[tid] = x11[tid]; bcl[tid] = bcat[tid]; }
  // zero pad cols {0,1,66,67} of IN (once; staging never touches them)
  if (tid < 192){
    int seg = tid >> 2, pc = tid & 3;
    int colp = (pc < 2) ? pc : pc + 64;
    *(f32x4*)(INL + seg*1088 + colp*16) = (f32x4){0.f,0.f,0.f,0.f};
  }

  f32x16 acc[4];
  #pragma unroll
  for (int pt=0;pt<4;pt++)
    #pragma unroll
    for (int e=0;e<16;e++) acc[pt][e] = 0.f;

  for (int q=0;q<2;++q){
    if (q) __syncthreads();      // all reads of W/IN from q0 complete before overwrite
    // stage W chunk q (fragment-major, linear): 4608 x 16B
    #pragma unroll
    for (int k=0;k<4;k++){
      int idx = tid + k*1024;
      gl2lds16(wgl + (size_t)q*73728 + (size_t)idx*16, WL + idx*16);
    }
    if (tid < 512){
      int idx = 4096 + tid;
      gl2lds16(wgl + (size_t)q*73728 + (size_t)idx*16, WL + idx*16);
    }
    // stage IN chunk q: 48 segs (12 rows x 4 slots), 3 per wave
    #pragma unroll
    for (int i=0;i<3;++i){
      int seg = w*3 + i;
      int row = seg >> 2, slot = seg & 3;
      int rg = r0 - 2 + row;
      char* dst = INL + seg*1088 + 32;
      if ((unsigned)rg < 64u){
        const char* src = (const char*)xb + ((((size_t)(g*64+rg))*8) + q*4 + slot)*1024 + lane*16;
        gl2lds16(src, dst + lane*16);
      } else {
        *(f32x4*)(dst + lane*16) = (f32x4){0.f,0.f,0.f,0.f};
      }
    }
    __syncthreads();
    if (conv == 0) conv_q<1>(INL, WL, ch2, rquad, cot, lh, l31, lane, acc);
    else           conv_q<2>(INL, WL, ch2, rquad, cot, lh, l31, lane, acc);
  }
  __syncthreads();

  // epilogue: bias + PReLU + residual (bf16 xb, L2-hot) -> BR swizzled
  {
    const float alpha = conv ? a2p[0] : a1p[0];
    const float* bbp = conv ? bb2 : bb1;
    #pragma unroll
    for (int rq=0;rq<4;++rq){
      int co0 = cot*32 + 8*rq + 4*lh;
      float b0 = bbp[co0], b1 = bbp[co0+1], b2 = bbp[co0+2], b3 = bbp[co0+3];
      int ch0 = conv*64 + co0;
      #pragma unroll
      for (int pt=0;pt<4;++pt){
        int prow = rquad*4 + pt;
        int colg = ch2*32 + l31;
        const char* rsrc = (const char*)xb + (((size_t)(g*64 + r0 + prow))*8 + (co0>>3))*1024
                           + colg*16 + (co0&7)*2;
        ushort4 rv = *(const ushort4*)rsrc;
        float v0 = acc[pt][rq*4+0] + b0; v0 = (v0>=0.f? v0 : alpha*v0) + bf2f(rv.x);
        float v1 = acc[pt][rq*4+1] + b1; v1 = (v1>=0.f? v1 : alpha*v1) + bf2f(rv.y);
        float v2 = acc[pt][rq*4+2] + b2; v2 = (v2>=0.f? v2 : alpha*v2) + bf2f(rv.z);
        float v3 = acc[pt][rq*4+3] + b3; v3 = (v3>=0.f? v3 : alpha*v3) + bf2f(rv.w);
        int px = prow*64 + colg;
        int addr = (px*256 + ch0*2) ^ ((px & 15) << 4);
        ushort4 pk; pk.x=f2bf(v0); pk.y=f2bf(v1); pk.z=f2bf(v2); pk.w=f2bf(v3);
        *(ushort4*)(BRL + addr) = pk;
      }
    }
  }
  __syncthreads();

  // cat 1x1 conv (K=128): A from WC (LDS), B from BR; reduce to wsum2/wsum2b + x2mean
  {
    f32x16 c2[2];
    #pragma unroll
    for (int t=0;t<2;t++)
      #pragma unroll
      for (int e=0;e<16;e++) c2[t][e] = 0.f;

    #pragma unroll
    for (int kfc=0;kfc<8;++kfc){
      const char* ap = WCL + (size_t)(kfc*2 + cot)*1024 + lane*16;
      short8v A0 = *(const short8v*)(ap);
      #pragma unroll
      for (int t=0;t<2;++t){
        int px = (w>>1)*64 + t*32 + l31;
        int addr = (px*256 + kfc*32 + lh*16) ^ ((px & 15) << 4);
        short8v B = *(const short8v*)(BRL + addr);
        c2[t] = MFMA32(A0, B, c2[t]);
      }
    }
    float u0 = 0.f, u1 = 0.f;
    #pragma unroll
    for (int reg=0;reg<16;++reg){
      int o = cot*32 + (reg&3) + 8*(reg>>2) + 4*lh;
      float xw = x11l[o], bc = bcl[o];
      u0 += xw*(c2[0][reg] + bc);
      u1 += xw*(c2[1][reg] + bc);
      float sv = c2[0][reg] + c2[1][reg];
      sv += __shfl_xor(sv, 1); sv += __shfl_xor(sv, 2);
      sv += __shfl_xor(sv, 4); sv += __shfl_xor(sv, 8); sv += __shfl_xor(sv, 16);
      if (l31 == 0) atomicAdd(&x2mean[g*64 + o], sv);
    }
    u0 += __shfl_xor(u0, 32);
    u1 += __shfl_xor(u1, 32);
    if (lh == 0){
      float* wp2 = (cot ? wsum2b : wsum2) + (size_t)g*4096 + strip*512 + (w>>1)*64 + l31;
      wp2[0]  = u0;
      wp2[32] = u1;
    }
  }
}

// ---------------- K5: x21-softmax + W = wsum2+wsum2b+S+sum_c crow*ccol*xb ; out = xb*sigmoid(W) --
__global__ __launch_bounds__(256) void k_final2(const unsigned short* __restrict__ xb,
                                                const float* __restrict__ sigbuf,
                                                const float* __restrict__ scsh,
                                                const float* __restrict__ x2mean,
                                                const float* __restrict__ bcat,
                                                const float* __restrict__ wsum2,
                                                const float* __restrict__ wsum2b,
                                                float* __restrict__ out){
  int blk = blockIdx.x;                 // g*16 + chunk
  int g = blk >> 4, chunk = blk & 15;
  int tid = threadIdx.x;
  __shared__ float x21s[64];
  __shared__ float crow[64*4];
  __shared__ float ccol[64*64];
  __shared__ float Ssm;
  const float* sgb = sigbuf + (size_t)g*8192;
  if (tid < 64){
    float mean = x2mean[g*64 + tid] * (1.f/4096.f) + bcat[tid];
    float mx = mean;
    for (int s=32; s; s>>=1) mx = fmaxf(mx, __shfl_xor(mx, s));
    float e = __expf(mean - mx);
    float se = e;
    for (int s=32; s; s>>=1) se += __shfl_xor(se, s);
    x21s[tid] = e/se;
  }
  for (int idx = tid; idx < 4096; idx += 256){
    int c = idx >> 6, col = idx & 63;
    ccol[idx] = sgb[c*128 + 64 + col];
  }
  __syncthreads();
  {
    int c = tid >> 2, rr = tid & 3;
    crow[tid] = x21s[c] * scsh[(g*64+c)*2] * sgb[c*128 + chunk*4 + rr];
  }
  if (tid < 64){
    float v = x21s[tid] * scsh[(g*64+tid)*2+1];
    for (int s=32; s; s>>=1) v += __shfl_xor(v, s);
    if (tid == 0) Ssm = v;
  }
  __syncthreads();
  int px = chunk*256 + tid;
  int rr = tid >> 6, col = tid & 63;
  int row = chunk*4 + rr;
  float xv[64];
  const char* xbg = (const char*)xb + (((size_t)(g*64 + row))*8)*1024 + col*16;
  #pragma unroll
  for (int slot=0;slot<8;slot++){
    short8v v8 = *(const short8v*)(xbg + slot*1024);
    #pragma unroll
    for (int e=0;e<8;e++) xv[slot*8+e] = bf2f((unsigned short)v8[e]);
  }
  float W = wsum2[(size_t)g*4096 + px] + wsum2b[(size_t)g*4096 + px] + Ssm;
  #pragma unroll
  for (int c=0;c<64;c++){
    W = fmaf(crow[c*4+rr]*ccol[c*64+col], xv[c], W);
  }
  float s = sigf(W);
  float* op = out + (size_t)(g*64)*HWPX + px;
  #pragma unroll
  for (int c=0;c<64;c++){
    op[(size_t)c*HWPX] = xv[c] * s;
  }
}

extern "C" void kernel_launch(void* const* d_in, const int* in_sizes, int n_in,
                              void* d_out, int out_size, void* d_ws, size_t ws_size,
                              hipStream_t stream) {
  const float* x     = (const float*)d_in[0];
  const float* w_hw  = (const float*)d_in[1];
  const float* b_hw  = (const float*)d_in[2];
  const float* gn_w  = (const float*)d_in[3];
  const float* gn_b  = (const float*)d_in[4];
  const float* w_b1  = (const float*)d_in[5];
  const float* b_b1  = (const float*)d_in[6];
  const float* a_b1  = (const float*)d_in[7];
  const float* w_b2  = (const float*)d_in[8];
  const float* b_b2  = (const float*)d_in[9];
  const float* a_b2  = (const float*)d_in[10];
  const float* w_cat = (const float*)d_in[11];
  const float* b_cat = (const float*)d_in[12];

  char* ws = (char*)d_ws;
  unsigned short* wimg  = (unsigned short*)(ws + 0);          // 147456
  unsigned short* wcimg = (unsigned short*)(ws + 147456);     // 16384
  float* x11    = (float*)(ws + 163840);                      // 256
  float* x2mean = (float*)(ws + 164096);                      // 32768
  float* scsh   = (float*)(ws + 196864);                      // 65536
  float* wsum2  = (float*)(ws + 262400);                      // 2097152
  float* wsum2b = (float*)(ws + 2359552);                     // 2097152
  float* hwbuf  = (float*)(ws + 4456704);                     // 4 MiB
  float* sigb   = (float*)(ws + 8651008);                     // 4 MiB
  unsigned short* xb = (unsigned short*)(ws + 16777216);      // 64 MiB
  float* out = (float*)d_out;

  hipFuncSetAttribute(reinterpret_cast<const void*>(k_convcat),
                      hipFuncAttributeMaxDynamicSharedMemorySize, 147968);

  k_pre  <<<1092, 256, 0, stream>>>(x, w_b1, w_b2, w_cat, gn_b, xb, hwbuf, wimg, wcimg,
                                    x11, x2mean);
  k_convcat<<<1152, 1024, 147968, stream>>>(xb, (const char*)wimg, (const char*)wcimg,
                                            hwbuf, w_hw, b_hw, sigb, gn_w, gn_b,
                                            b_b1, b_b2, a_b1, a_b2, b_cat, x11,
                                            wsum2, wsum2b, x2mean, scsh);
  k_final2<<<2048, 256, 0, stream>>>(xb, sigb, scsh, x2mean, b_cat, wsum2, wsum2b, out);
}

// Round 19
// 248.717 us; speedup vs baseline: 1.0990x; 1.0080x over previous
//
#include <hip/hip_runtime.h>
#include <hip/hip_bf16.h>

#define HWPX 4096

typedef __attribute__((ext_vector_type(8))) short short8v;
typedef __attribute__((ext_vector_type(4))) float f32x4;
typedef __attribute__((ext_vector_type(16))) float f32x16;
#define MFMA32(a,b,c) __builtin_amdgcn_mfma_f32_32x32x16_bf16(a,b,c,0,0,0)

__device__ __forceinline__ float sigf(float x){ return 1.0f/(1.0f+__expf(-x)); }
__device__ __forceinline__ unsigned short f2bf(float f){
  __hip_bfloat16 h = __float2bfloat16(f);
  unsigned short u; __builtin_memcpy(&u, &h, sizeof(u)); return u;
}
__device__ __forceinline__ float bf2f(unsigned short u){
  return __uint_as_float(((unsigned)u)<<16);
}
__device__ __forceinline__ void gl2lds16(const void* g, void* l){
  __builtin_amdgcn_global_load_lds((const __attribute__((address_space(1))) void*)g,
                                   (__attribute__((address_space(3))) void*)l, 16, 0, 0);
}

// ---------------- K1: merged prep (round-5 weight layout + x11) / rc / x2mean zero ----------------
__global__ __launch_bounds__(256) void k_pre(const float* __restrict__ x,
                                             const float* __restrict__ wb1,
                                             const float* __restrict__ wb2,
                                             const float* __restrict__ wcat,
                                             const float* __restrict__ gnb,
                                             unsigned short* __restrict__ xb,
                                             float* __restrict__ hwbuf,
                                             unsigned short* __restrict__ wimg,
                                             unsigned short* __restrict__ wcimg,
                                             float* __restrict__ x11,
                                             float* __restrict__ x2mean){
  int bid = blockIdx.x, tid = threadIdx.x;
  if (bid >= 1088){
    int idx = (bid - 1088)*2048 + tid*8;
    f32x4 z = {0.f,0.f,0.f,0.f};
    *(f32x4*)(x2mean + idx) = z;
    *(f32x4*)(x2mean + idx + 4) = z;
    return;
  }
  if (bid >= 1024){
    int bid2 = bid - 1024;
    for (int idx = bid2*256 + tid; idx < 73728; idx += 64*256){
      int f = idx >> 9, r = idx & 511, lane = r >> 3, j = r & 7;
      int qc = f / 36, rem = f % 36, tap = rem >> 2, kc = rem & 3;
      int q = qc >> 1, conv = qc & 1, kf = kc >> 1, cot = kc & 1;
      int co = cot*32 + (lane & 31);
      int ci = q*32 + kf*16 + (lane >> 5)*8 + j;
      const float* src = conv ? wb2 : wb1;
      wimg[idx] = f2bf(src[(co*64 + ci)*9 + tap]);
    }
    if (bid2 == 0){
      for (int idx = tid; idx < 8192; idx += 256){
        int f = idx >> 9, r = idx & 511, lane = r >> 3, j = r & 7;
        int kfc = f >> 1, cot = f & 1;
        int o = cot*32 + (lane & 31);
        int ch = kfc*16 + (lane >> 5)*8 + j;
        wcimg[idx] = f2bf(wcat[o*128 + ch]);
      }
      if (tid < 64){
        float g = gnb[tid];
        float m = g;
        for (int s=32; s; s>>=1) m = fmaxf(m, __shfl_xor(m, s));
        float e = __expf(g-m);
        float se = e;
        for (int s=32; s; s>>=1) se += __shfl_xor(se, s);
        x11[tid] = e/se;
      }
    }
    return;
  }
  // ---- rc ----
  int g = bid >> 3, slot = bid & 7;
  int col = tid & 63, wid = tid >> 6;
  __shared__ float rsm[8*64];
  __shared__ float csm[4*8*64];
  float colacc[8] = {0,0,0,0,0,0,0,0};
  const float* xbase = x + ((size_t)(g*64 + slot*8))*HWPX;
  for (int p=0;p<16;++p){
    int r = wid + 4*p;
    const float* src = xbase + r*64 + col;
    float v[8];
    #pragma unroll
    for (int e=0;e<8;e++) v[e] = src[(size_t)e*HWPX];
    unsigned pk[4];
    #pragma unroll
    for (int j=0;j<4;j++) pk[j] = (unsigned)f2bf(v[2*j]) | ((unsigned)f2bf(v[2*j+1])<<16);
    f32x4 st; __builtin_memcpy(&st, pk, 16);
    *(f32x4*)((char*)xb + (((size_t)(g*64+r))*8 + slot)*1024 + col*16) = st;
    #pragma unroll
    for (int e=0;e<8;e++){
      float s = v[e];
      s += __shfl_xor(s,1); s += __shfl_xor(s,2); s += __shfl_xor(s,4);
      s += __shfl_xor(s,8); s += __shfl_xor(s,16); s += __shfl_xor(s,32);
      if ((tid&63)==0) rsm[e*64+r] = s;
      colacc[e] += v[e];
    }
  }
  #pragma unroll
  for (int e=0;e<8;e++) csm[(wid*8+e)*64+col] = colacc[e];
  __syncthreads();
  float* hb = hwbuf + ((size_t)(g*64 + slot*8))*128;
  for (int idx=tid; idx<512; idx+=256){
    int e = idx>>6, r = idx&63;
    hb[e*128 + r] = rsm[e*64+r] * (1.0f/64.0f);
  }
  for (int idx=tid; idx<512; idx+=256){
    int e = idx>>6, c2 = idx&63;
    float s = csm[(0*8+e)*64+c2] + csm[(1*8+e)*64+c2] + csm[(2*8+e)*64+c2] + csm[(3*8+e)*64+c2];
    hb[e*128 + 64 + c2] = s * (1.0f/64.0f);
  }
}

// ---------------- conv compute (per q): dx-outer B-register reuse, A from LDS, cot-split ---------
template<int DIL>
__device__ __forceinline__ void conv_q(const char* INL, const char* WL,
                                       int ch2, int rquad, int cot, int lh, int l31, int lane,
                                       f32x16 (&acc)[4]){
  constexpr int conv = DIL - 1;
  constexpr int NROW = 4 + 2*DIL;
  #pragma unroll
  for (int kf=0; kf<2; ++kf){
    const char* ibase = INL + (kf*2 + lh)*1088 + (ch2*32 + 2 + l31)*16
                        + (rquad*4 + 2 - DIL)*4352;
    #pragma unroll
    for (int dxx=0; dxx<3; ++dxx){
      const char* ib = ibase + ((dxx-1)*DIL)*16;
      short8v Brow[NROW];
      #pragma unroll
      for (int i=0;i<NROW;++i) Brow[i] = *(const short8v*)(ib + i*4352);
      #pragma unroll
      for (int dyp=0;dyp<3;++dyp){
        int tap = dyp*3 + dxx;
        const char* wp = WL + (size_t)(((conv*9+tap)*4 + kf*2 + cot)*1024) + lane*16;
        short8v A0 = *(const short8v*)(wp);
        #pragma unroll
        for (int pt=0;pt<4;++pt)
          acc[pt] = MFMA32(A0, Brow[pt + dyp*DIL], acc[pt]);
      }
    }
  }
}

// ---------------- K4: conv blocks (0..1023, r12-exact) + gate2' half-blocks (1024..1279) ---------
// conv: 16 waves, round-5 staging, dx-outer B-reuse; LDS 147968, 1 block/CU.
// gate2' role: unit = (g, channel-half): hwmm for 32 o's (conflict-free) + sigmoid ->
//   sigl/sigbuf, then gate stats for the same 32 channels -> scsh. 256 units -> grid 1280 = 5 rounds.
__global__ __launch_bounds__(1024) void k_convcat(const unsigned short* __restrict__ xb,
                                                  const char* __restrict__ wgl,
                                                  const char* __restrict__ wcgl,
                                                  const float* __restrict__ hwbuf,
                                                  const float* __restrict__ whw,
                                                  const float* __restrict__ bhw,
                                                  float* __restrict__ sigbuf,
                                                  const float* __restrict__ gnw,
                                                  const float* __restrict__ gnb,
                                                  const float* __restrict__ bb1,
                                                  const float* __restrict__ bb2,
                                                  const float* __restrict__ a1p,
                                                  const float* __restrict__ a2p,
                                                  const float* __restrict__ bcat,
                                                  const float* __restrict__ x11,
                                                  float* __restrict__ wsum2,
                                                  float* __restrict__ wsum2b,
                                                  float* __restrict__ x2mean,
                                                  float* __restrict__ scsh){
  extern __shared__ char smem[];
  const int tid = threadIdx.x;

  if (blockIdx.x >= 1024){
    // ---------------- gate2' role (channel-half unit) ----------------
    int unit = blockIdx.x - 1024;          // 0..255
    int g = unit >> 1, half = unit & 1;
    int cbase = half*32;
    float* hwl  = (float*)smem;            // 8192 f   [i][128] linear (full)
    float* sigl = (float*)smem + 8192;     // 4160 f   [c_local][130] padded
    float* red  = (float*)smem + 12352;    // 256 f
    float* wl   = (float*)smem + 12608;    // 2080 f   [o_local][65] padded
    // stage hwbuf[g] (32KB) + w_hw half (padded)
    {
      const f32x4* src = (const f32x4*)(hwbuf + (size_t)g*8192);
      f32x4* dst = (f32x4*)hwl;
      dst[tid*2]   = src[tid*2];
      dst[tid*2+1] = src[tid*2+1];
      for (int idx = tid; idx < 2048; idx += 1024){
        int o = idx >> 6, i = idx & 63;
        wl[o*65 + i] = whw[(cbase + o)*64 + i];
      }
    }
    __syncthreads();
    // matmul: sig[o][p] = sigmoid(sum_i whw[o][i]*hw[i][p] + b[o]); o_local = tid&31
    {
      int o_local = tid & 31, seg = tid >> 5;   // seg 0..31, 4 positions each
      float acc[4];
      float bv = bhw[cbase + o_local];
      #pragma unroll
      for (int j=0;j<4;j++) acc[j] = bv;
      for (int i=0;i<64;++i){
        float wv = wl[o_local*65 + i];
        const float* hp = &hwl[i*128 + seg*4];
        #pragma unroll
        for (int j=0;j<4;j++) acc[j] = fmaf(wv, hp[j], acc[j]);
      }
      float* sgG = sigbuf + (size_t)g*8192 + (cbase + o_local)*128 + seg*4;
      #pragma unroll
      for (int j=0;j<4;j++){
        float sg = sigf(acc[j]);
        sigl[o_local*130 + seg*4 + j] = sg;
        sgG[j] = sg;
      }
    }
    __syncthreads();
    // gate stats: 32 channels (4 slots) x 4 row-quarters across 16 waves
    {
      int col = tid & 63, wid = tid >> 6, lane = tid & 63;
      int slot_l = wid >> 2, quarter = wid & 3;
      int slot = (cbase >> 3) + slot_l;
      float s[8] = {0,0,0,0,0,0,0,0}, s2[8] = {0,0,0,0,0,0,0,0};
      const char* base = (const char*)xb + (((size_t)(g*64))*8 + slot)*1024 + col*16;
      for (int p=0;p<16;++p){
        int row = quarter*16 + p;
        short8v xv = *(const short8v*)(base + (size_t)row*8192);
        #pragma unroll
        for (int e=0;e<8;e++){
          int cl = slot_l*8 + e;
          float v = bf2f((unsigned short)xv[e]) * sigl[cl*130 + row] * sigl[cl*130 + 64 + col];
          s[e] += v; s2[e] = fmaf(v, v, s2[e]);
        }
      }
      #pragma unroll
      for (int e=0;e<8;e++){
        #pragma unroll
        for (int off=1; off<64; off<<=1){ s[e] += __shfl_xor(s[e], off); s2[e] += __shfl_xor(s2[e], off); }
      }
      if (lane == 0){
        #pragma unroll
        for (int e=0;e<8;e++){ red[wid*16+e] = s[e]; red[wid*16+8+e] = s2[e]; }
      }
      __syncthreads();
      if (tid < 32){
        int cl = tid, sl = cl >> 3, e = cl & 7;
        float S  = red[(sl*4+0)*16 + e]     + red[(sl*4+1)*16 + e]
                 + red[(sl*4+2)*16 + e]     + red[(sl*4+3)*16 + e];
        float S2 = red[(sl*4+0)*16 + 8 + e] + red[(sl*4+1)*16 + 8 + e]
                 + red[(sl*4+2)*16 + 8 + e] + red[(sl*4+3)*16 + 8 + e];
        float mu = S*(1.f/4096.f);
        float var = S2*(1.f/4096.f) - mu*mu;
        int c = cbase + cl;
        float scale = rsqrtf(var + 1e-5f) * gnw[c];
        scsh[(g*64+c)*2]   = scale;
        scsh[(g*64+c)*2+1] = gnb[c] - mu*scale;
      }
    }
    return;
  }

  // ---------------- conv role (byte-identical to round 12) ----------------
  char* INL = smem;                      // 52224
  char* WL  = smem + 52224;              // 73728
  char* BRL = smem;                      // 131072 (epilogue overlay)
  char* WCL = smem + 131072;             // 16384
  float* x11l = (float*)(smem + 147456); // 64
  float* bcl  = x11l + 64;               // 64

  const int g = blockIdx.x >> 3;
  const int strip = blockIdx.x & 7;
  const int r0 = strip*8;
  const int w = tid >> 6;
  const int lane = tid & 63;
  const int l31 = lane & 31;
  const int lh  = lane >> 5;
  const int conv = w >> 3;
  const int ch2 = (w >> 2) & 1;
  const int rquad = (w >> 1) & 1;
  const int cot = w & 1;

  // stage wcat fragments (persistent): 1024 x 16B, one per thread
  gl2lds16(wcgl + (size_t)tid*16, WCL + tid*16);
  if (tid < 64){ x11l[tid] = x11[tid]; bcl[tid] = bcat[tid]; }
  // zero pad cols {0,1,66,67} of IN (once; staging never touches them)
  if (tid < 192){
    int seg = tid >> 2, pc = tid & 3;
    int colp = (pc < 2) ? pc : pc + 64;
    *(f32x4*)(INL + seg*1088 + colp*16) = (f32x4){0.f,0.f,0.f,0.f};
  }

  f32x16 acc[4];
  #pragma unroll
  for (int pt=0;pt<4;pt++)
    #pragma unroll
    for (int e=0;e<16;e++) acc[pt][e] = 0.f;

  for (int q=0;q<2;++q){
    if (q) __syncthreads();      // all reads of W/IN from q0 complete before overwrite
    // stage W chunk q (fragment-major, linear): 4608 x 16B
    #pragma unroll
    for (int k=0;k<4;k++){
      int idx = tid + k*1024;
      gl2lds16(wgl + (size_t)q*73728 + (size_t)idx*16, WL + idx*16);
    }
    if (tid < 512){
      int idx = 4096 + tid;
      gl2lds16(wgl + (size_t)q*73728 + (size_t)idx*16, WL + idx*16);
    }
    // stage IN chunk q: 48 segs (12 rows x 4 slots), 3 per wave
    #pragma unroll
    for (int i=0;i<3;++i){
      int seg = w*3 + i;
      int row = seg >> 2, slot = seg & 3;
      int rg = r0 - 2 + row;
      char* dst = INL + seg*1088 + 32;
      if ((unsigned)rg < 64u){
        const char* src = (const char*)xb + ((((size_t)(g*64+rg))*8) + q*4 + slot)*1024 + lane*16;
        gl2lds16(src, dst + lane*16);
      } else {
        *(f32x4*)(dst + lane*16) = (f32x4){0.f,0.f,0.f,0.f};
      }
    }
    __syncthreads();
    if (conv == 0) conv_q<1>(INL, WL, ch2, rquad, cot, lh, l31, lane, acc);
    else           conv_q<2>(INL, WL, ch2, rquad, cot, lh, l31, lane, acc);
  }
  __syncthreads();

  // epilogue: bias + PReLU + residual (bf16 xb, L2-hot) -> BR swizzled
  {
    const float alpha = conv ? a2p[0] : a1p[0];
    const float* bbp = conv ? bb2 : bb1;
    #pragma unroll
    for (int rq=0;rq<4;++rq){
      int co0 = cot*32 + 8*rq + 4*lh;
      float b0 = bbp[co0], b1 = bbp[co0+1], b2 = bbp[co0+2], b3 = bbp[co0+3];
      int ch0 = conv*64 + co0;
      #pragma unroll
      for (int pt=0;pt<4;++pt){
        int prow = rquad*4 + pt;
        int colg = ch2*32 + l31;
        const char* rsrc = (const char*)xb + (((size_t)(g*64 + r0 + prow))*8 + (co0>>3))*1024
                           + colg*16 + (co0&7)*2;
        ushort4 rv = *(const ushort4*)rsrc;
        float v0 = acc[pt][rq*4+0] + b0; v0 = (v0>=0.f? v0 : alpha*v0) + bf2f(rv.x);
        float v1 = acc[pt][rq*4+1] + b1; v1 = (v1>=0.f? v1 : alpha*v1) + bf2f(rv.y);
        float v2 = acc[pt][rq*4+2] + b2; v2 = (v2>=0.f? v2 : alpha*v2) + bf2f(rv.z);
        float v3 = acc[pt][rq*4+3] + b3; v3 = (v3>=0.f? v3 : alpha*v3) + bf2f(rv.w);
        int px = prow*64 + colg;
        int addr = (px*256 + ch0*2) ^ ((px & 15) << 4);
        ushort4 pk; pk.x=f2bf(v0); pk.y=f2bf(v1); pk.z=f2bf(v2); pk.w=f2bf(v3);
        *(ushort4*)(BRL + addr) = pk;
      }
    }
  }
  __syncthreads();

  // cat 1x1 conv (K=128): A from WC (LDS), B from BR; reduce to wsum2/wsum2b + x2mean
  {
    f32x16 c2[2];
    #pragma unroll
    for (int t=0;t<2;t++)
      #pragma unroll
      for (int e=0;e<16;e++) c2[t][e] = 0.f;

    #pragma unroll
    for (int kfc=0;kfc<8;++kfc){
      const char* ap = WCL + (size_t)(kfc*2 + cot)*1024 + lane*16;
      short8v A0 = *(const short8v*)(ap);
      #pragma unroll
      for (int t=0;t<2;++t){
        int px = (w>>1)*64 + t*32 + l31;
        int addr = (px*256 + kfc*32 + lh*16) ^ ((px & 15) << 4);
        short8v B = *(const short8v*)(BRL + addr);
        c2[t] = MFMA32(A0, B, c2[t]);
      }
    }
    float u0 = 0.f, u1 = 0.f;
    #pragma unroll
    for (int reg=0;reg<16;++reg){
      int o = cot*32 + (reg&3) + 8*(reg>>2) + 4*lh;
      float xw = x11l[o], bc = bcl[o];
      u0 += xw*(c2[0][reg] + bc);
      u1 += xw*(c2[1][reg] + bc);
      float sv = c2[0][reg] + c2[1][reg];
      sv += __shfl_xor(sv, 1); sv += __shfl_xor(sv, 2);
      sv += __shfl_xor(sv, 4); sv += __shfl_xor(sv, 8); sv += __shfl_xor(sv, 16);
      if (l31 == 0) atomicAdd(&x2mean[g*64 + o], sv);
    }
    u0 += __shfl_xor(u0, 32);
    u1 += __shfl_xor(u1, 32);
    if (lh == 0){
      float* wp2 = (cot ? wsum2b : wsum2) + (size_t)g*4096 + strip*512 + (w>>1)*64 + l31;
      wp2[0]  = u0;
      wp2[32] = u1;
    }
  }
}

// ---------------- K5: x21-softmax + W = wsum2+wsum2b+S+sum_c crow*ccol*xb ; out = xb*sigmoid(W) --
__global__ __launch_bounds__(256) void k_final2(const unsigned short* __restrict__ xb,
                                                const float* __restrict__ sigbuf,
                                                const float* __restrict__ scsh,
                                                const float* __restrict__ x2mean,
                                                const float* __restrict__ bcat,
                                                const float* __restrict__ wsum2,
                                                const float* __restrict__ wsum2b,
                                                float* __restrict__ out){
  int blk = blockIdx.x;                 // g*16 + chunk
  int g = blk >> 4, chunk = blk & 15;
  int tid = threadIdx.x;
  __shared__ float x21s[64];
  __shared__ float crow[64*4];
  __shared__ float ccol[64*64];
  __shared__ float Ssm;
  const float* sgb = sigbuf + (size_t)g*8192;
  if (tid < 64){
    float mean = x2mean[g*64 + tid] * (1.f/4096.f) + bcat[tid];
    float mx = mean;
    for (int s=32; s; s>>=1) mx = fmaxf(mx, __shfl_xor(mx, s));
    float e = __expf(mean - mx);
    float se = e;
    for (int s=32; s; s>>=1) se += __shfl_xor(se, s);
    x21s[tid] = e/se;
  }
  for (int idx = tid; idx < 4096; idx += 256){
    int c = idx >> 6, col = idx & 63;
    ccol[idx] = sgb[c*128 + 64 + col];
  }
  __syncthreads();
  {
    int c = tid >> 2, rr = tid & 3;
    crow[tid] = x21s[c] * scsh[(g*64+c)*2] * sgb[c*128 + chunk*4 + rr];
  }
  if (tid < 64){
    float v = x21s[tid] * scsh[(g*64+tid)*2+1];
    for (int s=32; s; s>>=1) v += __shfl_xor(v, s);
    if (tid == 0) Ssm = v;
  }
  __syncthreads();
  int px = chunk*256 + tid;
  int rr = tid >> 6, col = tid & 63;
  int row = chunk*4 + rr;
  float xv[64];
  const char* xbg = (const char*)xb + (((size_t)(g*64 + row))*8)*1024 + col*16;
  #pragma unroll
  for (int slot=0;slot<8;slot++){
    short8v v8 = *(const short8v*)(xbg + slot*1024);
    #pragma unroll
    for (int e=0;e<8;e++) xv[slot*8+e] = bf2f((unsigned short)v8[e]);
  }
  float W = wsum2[(size_t)g*4096 + px] + wsum2b[(size_t)g*4096 + px] + Ssm;
  #pragma unroll
  for (int c=0;c<64;c++){
    W = fmaf(crow[c*4+rr]*ccol[c*64+col], xv[c], W);
  }
  float s = sigf(W);
  float* op = out + (size_t)(g*64)*HWPX + px;
  #pragma unroll
  for (int c=0;c<64;c++){
    op[(size_t)c*HWPX] = xv[c] * s;
  }
}

extern "C" void kernel_launch(void* const* d_in, const int* in_sizes, int n_in,
                              void* d_out, int out_size, void* d_ws, size_t ws_size,
                              hipStream_t stream) {
  const float* x     = (const float*)d_in[0];
  const float* w_hw  = (const float*)d_in[1];
  const float* b_hw  = (const float*)d_in[2];
  const float* gn_w  = (const float*)d_in[3];
  const float* gn_b  = (const float*)d_in[4];
  const float* w_b1  = (const float*)d_in[5];
  const float* b_b1  = (const float*)d_in[6];
  const float* a_b1  = (const float*)d_in[7];
  const float* w_b2  = (const float*)d_in[8];
  const float* b_b2  = (const float*)d_in[9];
  const float* a_b2  = (const float*)d_in[10];
  const float* w_cat = (const float*)d_in[11];
  const float* b_cat = (const float*)d_in[12];

  char* ws = (char*)d_ws;
  unsigned short* wimg  = (unsigned short*)(ws + 0);          // 147456
  unsigned short* wcimg = (unsigned short*)(ws + 147456);     // 16384
  float* x11    = (float*)(ws + 163840);                      // 256
  float* x2mean = (float*)(ws + 164096);                      // 32768
  float* scsh   = (float*)(ws + 196864);                      // 65536
  float* wsum2  = (float*)(ws + 262400);                      // 2097152
  float* wsum2b = (float*)(ws + 2359552);                     // 2097152
  float* hwbuf  = (float*)(ws + 4456704);                     // 4 MiB
  float* sigb   = (float*)(ws + 8651008);                     // 4 MiB
  unsigned short* xb = (unsigned short*)(ws + 16777216);      // 64 MiB
  float* out = (float*)d_out;

  hipFuncSetAttribute(reinterpret_cast<const void*>(k_convcat),
                      hipFuncAttributeMaxDynamicSharedMemorySize, 147968);

  k_pre  <<<1092, 256, 0, stream>>>(x, w_b1, w_b2, w_cat, gn_b, xb, hwbuf, wimg, wcimg,
                                    x11, x2mean);
  k_convcat<<<1280, 1024, 147968, stream>>>(xb, (const char*)wimg, (const char*)wcimg,
                                            hwbuf, w_hw, b_hw, sigb, gn_w, gn_b,
                                            b_b1, b_b2, a_b1, a_b2, b_cat, x11,
                                            wsum2, wsum2b, x2mean, scsh);
  k_final2<<<2048, 256, 0, stream>>>(xb, sigb, scsh, x2mean, b_cat, wsum2, wsum2b, out);
}